// Round 1
// baseline (428.762 us; speedup 1.0000x reference)
//
#include <hip/hip_runtime.h>

// ---------------------------------------------------------------------------
// Problem constants
// ---------------------------------------------------------------------------
// NL=16, NS=256, NE=100, B=2, P=2, T=12
// x:   (2,2,12,16,256)  fp32   [d_in 0]
// K:   (256,256,16)     fp32   [d_in 1]   K[X, x, c], j = x*16+c contiguous
// Q:   (256,256,16)     fp32   [d_in 2]
// V:   (256,256,16)     fp32   [d_in 3]   V[X, x, c]
// Aoo: (256,256)        fp32   [d_in 4]
// Ann: (100,)           fp32   [d_in 5]
// Aon: (256,256,100)    fp32   [d_in 6]
// Ano: (256,256,100)    fp32   [d_in 7]
// w:   (256,)           fp32   [d_in 8]
// out: (2,2,1,16) = 64 fp32

using short8 = __attribute__((ext_vector_type(8))) short;
using f32x4  = __attribute__((ext_vector_type(4))) float;

__device__ inline unsigned short f2b(float f) {
    unsigned u = __builtin_bit_cast(unsigned, f);
    u += 0x7fffu + ((u >> 16) & 1u);   // RNE to bf16
    return (unsigned short)(u >> 16);
}
__device__ inline unsigned pk2(float a, float b) {
    return (unsigned)f2b(a) | ((unsigned)f2b(b) << 16);
}
__device__ inline float blo(unsigned v) { return __builtin_bit_cast(float, v << 16); }
__device__ inline float bhi(unsigned v) { return __builtin_bit_cast(float, v & 0xffff0000u); }
__device__ inline float clip1(float v) { return fminf(fmaxf(v, -1.f), 1.f); }

// ---------------------------------------------------------------------------
// P0: convert K,Q -> bf16 (Kb, Qb) and build u_t[bt][x*16+c] = x[bt][c][x]
// grid 2096 x 256
// ---------------------------------------------------------------------------
__global__ void prep_kernel(const float* __restrict__ K, const float* __restrict__ Q,
                            const float* __restrict__ xin,
                            unsigned short* __restrict__ Kb, unsigned short* __restrict__ Qb,
                            float* __restrict__ u_t)
{
    int b = blockIdx.x, t = threadIdx.x;
    if (b < 2048) {
        bool isK = (b < 1024);
        int bb = isK ? b : b - 1024;
        int i = bb * 1024 + t * 4;
        const float4 f = ((const float4*)(isK ? K : Q))[i >> 2];
        short4 v;
        v.x = (short)f2b(f.x); v.y = (short)f2b(f.y);
        v.z = (short)f2b(f.z); v.w = (short)f2b(f.w);
        *(short4*)((isK ? Kb : Qb) + i) = v;
    } else {
        int bt = b - 2048;                    // 0..47
        const float* src = xin + (size_t)bt * 4096;
        float* dst = u_t + (size_t)bt * 4096;
        int xx = t;                           // 0..255
        #pragma unroll
        for (int c = 0; c < 16; ++c)
            dst[xx * 16 + c] = src[c * 256 + xx];
    }
}

// ---------------------------------------------------------------------------
// W2[X][n] = sum_x w[x] * clip(Aon[X,x,n]) ;  grid 256 x 128
// ---------------------------------------------------------------------------
__global__ void w2_kernel(const float* __restrict__ Aon, const float* __restrict__ wv,
                          float* __restrict__ W2)
{
    int X = blockIdx.x, n = threadIdx.x;
    if (n >= 100) return;
    const float* base = Aon + (size_t)X * 25600 + n;
    float acc = 0.f;
    for (int b = 0; b < 256; ++b)
        acc += wv[b] * clip1(base[(size_t)b * 100]);
    W2[X * 100 + n] = acc;
}

// ---------------------------------------------------------------------------
// kvt[bt][X][Y] = sum_j Kb[X,j]*u[j] * Qb[Y,j]   (bf16 MFMA, fp32 acc)
// grid 192 (= 48 bt * 4 tiles of 128x128), block 256 (4 waves, each 64x64)
// ---------------------------------------------------------------------------
__global__ __launch_bounds__(256) void gemm_kvt(const unsigned short* __restrict__ Kb,
                                                const unsigned short* __restrict__ Qb,
                                                const float* __restrict__ u_t,
                                                float* __restrict__ kvt)
{
    int bt   = blockIdx.x >> 2;
    int tile = blockIdx.x & 3;
    int Xb = (tile >> 1) * 128, Yb = (tile & 1) * 128;

    __shared__ float u_s[4096];                 // 16 KB
    __shared__ unsigned short As[128][40];      // padded stride 40 (80B) -> 2-way max
    __shared__ unsigned short Bs[128][40];

    int tid = threadIdx.x;
    {   // load u (per-batch scale) once
        const float4* us = (const float4*)(u_t + (size_t)bt * 4096);
        float4* ud = (float4*)u_s;
        for (int i = tid; i < 1024; i += 256) ud[i] = us[i];
    }
    __syncthreads();

    int wave = tid >> 6, lane = tid & 63;
    int wr = (wave >> 1) * 64, wc = (wave & 1) * 64;
    int lrow = lane & 15, kg = lane >> 4;

    f32x4 zero = {0.f, 0.f, 0.f, 0.f};
    f32x4 acc[4][4];
    #pragma unroll
    for (int m = 0; m < 4; ++m)
        #pragma unroll
        for (int n = 0; n < 4; ++n) acc[m][n] = zero;

    int r = tid >> 1, half = tid & 1;

    for (int kk = 0; kk < 128; ++kk) {
        int k0 = kk * 32;
        int j0 = k0 + half * 16;
        // ---- stage A = Kb * u  (16 bf16 per thread) ----
        const uint4* ka = (const uint4*)(Kb + (size_t)(Xb + r) * 4096 + j0);
        uint4 kv0 = ka[0], kv1 = ka[1];
        float4 u0 = *(const float4*)(u_s + j0);
        float4 u1 = *(const float4*)(u_s + j0 + 4);
        float4 u2 = *(const float4*)(u_s + j0 + 8);
        float4 u3 = *(const float4*)(u_s + j0 + 12);
        uint4 o0, o1;
        o0.x = pk2(blo(kv0.x) * u0.x, bhi(kv0.x) * u0.y);
        o0.y = pk2(blo(kv0.y) * u0.z, bhi(kv0.y) * u0.w);
        o0.z = pk2(blo(kv0.z) * u1.x, bhi(kv0.z) * u1.y);
        o0.w = pk2(blo(kv0.w) * u1.z, bhi(kv0.w) * u1.w);
        o1.x = pk2(blo(kv1.x) * u2.x, bhi(kv1.x) * u2.y);
        o1.y = pk2(blo(kv1.y) * u2.z, bhi(kv1.y) * u2.w);
        o1.z = pk2(blo(kv1.z) * u3.x, bhi(kv1.z) * u3.y);
        o1.w = pk2(blo(kv1.w) * u3.z, bhi(kv1.w) * u3.w);
        *(uint4*)&As[r][half * 16]     = o0;
        *(uint4*)&As[r][half * 16 + 8] = o1;
        // ---- stage B = Qb (raw bf16 copy) ----
        const uint4* qa = (const uint4*)(Qb + (size_t)(Yb + r) * 4096 + j0);
        uint4 q0 = qa[0], q1 = qa[1];
        *(uint4*)&Bs[r][half * 16]     = q0;
        *(uint4*)&Bs[r][half * 16 + 8] = q1;
        __syncthreads();

        // ---- MFMA: 4x4 fragments of 16x16x32 ----
        short8 af[4], bf_[4];
        #pragma unroll
        for (int m = 0; m < 4; ++m)
            af[m] = *(const short8*)&As[wr + m * 16 + lrow][kg * 8];
        #pragma unroll
        for (int n = 0; n < 4; ++n)
            bf_[n] = *(const short8*)&Bs[wc + n * 16 + lrow][kg * 8];
        #pragma unroll
        for (int m = 0; m < 4; ++m)
            #pragma unroll
            for (int n = 0; n < 4; ++n)
                acc[m][n] = __builtin_amdgcn_mfma_f32_16x16x32_bf16(af[m], bf_[n], acc[m][n], 0, 0, 0);
        __syncthreads();
    }

    // epilogue: D layout col = lane&15, row = (lane>>4)*4 + reg
    float* outp = kvt + (size_t)bt * 65536;
    int row0 = Xb + wr + kg * 4;
    int col0 = Yb + wc + lrow;
    #pragma unroll
    for (int m = 0; m < 4; ++m)
        #pragma unroll
        for (int n = 0; n < 4; ++n)
            #pragma unroll
            for (int rr = 0; rr < 4; ++rr)
                outp[(size_t)(row0 + m * 16 + rr) * 256 + col0 + n * 16] = acc[m][n][rr];
}

// ---------------------------------------------------------------------------
// Sp[cb][bp][J][n] = sum_{k in chunk cb} clip(Ano_f[k][n]) * kvt[bp*12+J][k]
// chunk = 128 k, grid 512 x 256 (wave w = bp)
// ---------------------------------------------------------------------------
__global__ __launch_bounds__(256) void s_partial(const float* __restrict__ Ano,
                                                 const float* __restrict__ kvt,
                                                 float* __restrict__ Sp)
{
    __shared__ float ano_s[12800];          // [128][100]
    int cb = blockIdx.x;
    int k0 = cb * 128;
    int tid = threadIdx.x;
    {
        const float4* src = (const float4*)(Ano + (size_t)k0 * 100);
        float4* dst = (float4*)ano_s;
        for (int i = tid; i < 3200; i += 256) {
            float4 f = src[i];
            f.x = clip1(f.x); f.y = clip1(f.y); f.z = clip1(f.z); f.w = clip1(f.w);
            dst[i] = f;
        }
    }
    __syncthreads();

    int lane = tid & 63;
    int bp = __builtin_amdgcn_readfirstlane(tid >> 6);
    bool has2 = lane < 36;
    float acc0[11], acc1[11];
    #pragma unroll
    for (int J = 0; J < 11; ++J) { acc0[J] = 0.f; acc1[J] = 0.f; }

    const float* kvbase = kvt + (size_t)bp * 12 * 65536 + k0;
    for (int k = 0; k < 128; ++k) {
        float a0 = ano_s[k * 100 + lane];
        float a1 = has2 ? ano_s[k * 100 + 64 + lane] : 0.f;
        #pragma unroll
        for (int J = 0; J < 11; ++J) {
            float kv = kvbase[(size_t)J * 65536 + k];
            acc0[J] += kv * a0;
            acc1[J] += kv * a1;
        }
    }
    float* outb = Sp + ((size_t)cb * 4 + bp) * 1100;
    #pragma unroll
    for (int J = 0; J < 11; ++J) {
        outb[J * 100 + lane] = acc0[J];
        if (has2) outb[J * 100 + 64 + lane] = acc1[J];
    }
}

// S[bp*11+J][n] = sum_cb Sp[cb][bp][J][n] ; grid 44 x 128
__global__ void reduce_s(const float* __restrict__ Sp, float* __restrict__ S)
{
    int bp = blockIdx.x / 11, J = blockIdx.x % 11;
    int t = threadIdx.x;
    if (t >= 100) return;
    float acc = 0.f;
    for (int c = 0; c < 512; ++c)
        acc += Sp[((size_t)c * 4 + bp) * 1100 + J * 100 + t];
    S[(bp * 11 + J) * 100 + t] = acc;
}

// c2[bp][n] = S[bp][10][n] + sum_J A_seq[9-J][n] * S[bp][J][n] ; 1 x 512
__global__ void c2_kernel(const float* __restrict__ S, const float* __restrict__ Ann,
                          float* __restrict__ c2)
{
    int t = threadIdx.x;
    int bp = t >> 7, n = t & 127;
    if (n >= 100) return;
    float a = Ann[n];
    float seq[10];
    float v = a;
    seq[0] = v;
    #pragma unroll
    for (int s = 1; s < 10; ++s) { v = clip1(v * a); seq[s] = v; }
    float r = S[(bp * 11 + 10) * 100 + n];
    #pragma unroll
    for (int J = 0; J < 10; ++J)
        r += seq[9 - J] * S[(bp * 11 + J) * 100 + n];
    c2[bp * 100 + n] = r;
}

// hw[bp][X] = sum_x w[x]*Aoo[X,x]*kvt11[X,x] + sum_n c2[bp][n]*W2[X][n]
// grid 256 (bp*64 + Xg) x 256 (wave = one X)
__global__ __launch_bounds__(256) void hw_kernel(const float* __restrict__ Aoo,
                                                 const float* __restrict__ wv,
                                                 const float* __restrict__ kvt,
                                                 const float* __restrict__ W2,
                                                 const float* __restrict__ c2,
                                                 float* __restrict__ hw)
{
    int bp = blockIdx.x >> 6, Xg = blockIdx.x & 63;
    int wave = threadIdx.x >> 6, lane = threadIdx.x & 63;
    int X = Xg * 4 + wave;
    const float* kv = kvt + ((size_t)bp * 12 + 11) * 65536 + (size_t)X * 256;
    const float* ao = Aoo + (size_t)X * 256;
    float red = 0.f;
    #pragma unroll
    for (int q = 0; q < 4; ++q) {
        int xx = q * 64 + lane;
        red += wv[xx] * ao[xx] * kv[xx];
    }
    red += c2[bp * 100 + lane] * W2[X * 100 + lane];
    if (lane < 36)
        red += c2[bp * 100 + 64 + lane] * W2[X * 100 + 64 + lane];
    #pragma unroll
    for (int off = 32; off; off >>= 1) red += __shfl_xor(red, off);
    if (lane == 0) hw[bp * 256 + X] = red;
}

// vh[bp][j] = sum_X hw[bp][X] * V[X][j] ; grid 16 x 256 (bp*4 + jg)
__global__ __launch_bounds__(256) void vh_kernel(const float* __restrict__ V,
                                                 const float* __restrict__ hw,
                                                 float* __restrict__ vh)
{
    int bp = blockIdx.x >> 2, jg = blockIdx.x & 3;
    int t = threadIdx.x;
    float a0 = 0.f, a1 = 0.f, a2 = 0.f, a3 = 0.f;
    const float* hb = hw + bp * 256;
    const float* vb = V + jg * 1024 + t;
    for (int X = 0; X < 256; ++X) {
        float h = hb[X];
        const float* vr = vb + (size_t)X * 4096;
        a0 += h * vr[0];
        a1 += h * vr[256];
        a2 += h * vr[512];
        a3 += h * vr[768];
    }
    float* o = vh + bp * 4096 + jg * 1024 + t;
    o[0] = a0; o[256] = a1; o[512] = a2; o[768] = a3;
}

// y[bp*16+c] = sum_x xlast[bp][c][x] * vh[bp][x*16+c] ; 1 x 64
__global__ void y_kernel(const float* __restrict__ xin, const float* __restrict__ vh,
                         float* __restrict__ out)
{
    int t = threadIdx.x;
    if (t >= 64) return;
    int bp = t >> 4, c = t & 15;
    const float* xl = xin + ((size_t)bp * 12 + 11) * 4096 + c * 256;
    const float* vb = vh + bp * 4096 + c;
    float acc = 0.f;
    for (int xx = 0; xx < 256; ++xx)
        acc += xl[xx] * vb[xx * 16];
    out[t] = acc;
}

// ---------------------------------------------------------------------------
extern "C" void kernel_launch(void* const* d_in, const int* in_sizes, int n_in,
                              void* d_out, int out_size, void* d_ws, size_t ws_size,
                              hipStream_t stream)
{
    const float* x   = (const float*)d_in[0];
    const float* K   = (const float*)d_in[1];
    const float* Q   = (const float*)d_in[2];
    const float* V   = (const float*)d_in[3];
    const float* Aoo = (const float*)d_in[4];
    const float* Ann = (const float*)d_in[5];
    const float* Aon = (const float*)d_in[6];
    const float* Ano = (const float*)d_in[7];
    const float* wv  = (const float*)d_in[8];
    float* out = (float*)d_out;

    char* ws = (char*)d_ws;
    const size_t o_Qb  = 0;                        // 1M bf16 = 2 MB
    const size_t o_Kb  = o_Qb  + (size_t)2  * 1024 * 1024;
    const size_t o_ut  = o_Kb  + (size_t)2  * 1024 * 1024;   // 48*4096 f32
    const size_t o_kvt = o_ut  + (size_t)48 * 4096 * 4;      // 48*65536 f32
    const size_t o_Sp  = o_kvt + (size_t)48 * 65536 * 4;     // 512*4400 f32
    const size_t o_S   = o_Sp  + (size_t)512 * 4400 * 4;     // 4400 f32
    const size_t o_c2  = o_S   + (size_t)4400 * 4;           // 400 f32
    const size_t o_W2  = o_c2  + (size_t)400 * 4 + 16;       // 25600 f32
    const size_t o_hw  = o_W2  + (size_t)25600 * 4;          // 1024 f32
    const size_t o_vh  = o_hw  + (size_t)1024 * 4;           // 16384 f32

    unsigned short* Kb = (unsigned short*)(ws + o_Kb);
    unsigned short* Qb = (unsigned short*)(ws + o_Qb);
    float* u_t = (float*)(ws + o_ut);
    float* kvt = (float*)(ws + o_kvt);
    float* Sp  = (float*)(ws + o_Sp);
    float* S   = (float*)(ws + o_S);
    float* c2  = (float*)(ws + o_c2);
    float* W2  = (float*)(ws + o_W2);
    float* hw  = (float*)(ws + o_hw);
    float* vh  = (float*)(ws + o_vh);

    hipLaunchKernelGGL(prep_kernel, dim3(2096), dim3(256), 0, stream, K, Q, x, Kb, Qb, u_t);
    hipLaunchKernelGGL(w2_kernel,   dim3(256),  dim3(128), 0, stream, Aon, wv, W2);
    hipLaunchKernelGGL(gemm_kvt,    dim3(192),  dim3(256), 0, stream, Kb, Qb, u_t, kvt);
    hipLaunchKernelGGL(s_partial,   dim3(512),  dim3(256), 0, stream, Ano, kvt, Sp);
    hipLaunchKernelGGL(reduce_s,    dim3(44),   dim3(128), 0, stream, Sp, S);
    hipLaunchKernelGGL(c2_kernel,   dim3(1),    dim3(512), 0, stream, S, Ann, c2);
    hipLaunchKernelGGL(hw_kernel,   dim3(256),  dim3(256), 0, stream, Aoo, wv, kvt, W2, c2, hw);
    hipLaunchKernelGGL(vh_kernel,   dim3(16),   dim3(256), 0, stream, V, hw, vh);
    hipLaunchKernelGGL(y_kernel,    dim3(1),    dim3(64),  0, stream, x, vh, out);
}

// Round 2
// 248.381 us; speedup vs baseline: 1.7262x; 1.7262x over previous
//
#include <hip/hip_runtime.h>
#include <hip/hip_bf16.h>

// ---------------------------------------------------------------------------
// NL=16, NS=256, NE=100, B=2, P=2, T=12
// x:   (2,2,12,16,256)  fp32   [d_in 0]
// K:   (256,256,16)     fp32   [d_in 1]   K[X, x, c], j = x*16+c contiguous
// Q:   (256,256,16)     fp32   [d_in 2]
// V:   (256,256,16)     fp32   [d_in 3]
// Aoo: (256,256)        fp32   [d_in 4]
// Ann: (100,)           fp32   [d_in 5]
// Aon: (256,256,100)    fp32   [d_in 6]
// Ano: (256,256,100)    fp32   [d_in 7]
// w:   (256,)           fp32   [d_in 8]
// out: (2,2,1,16) = 64 fp32

using short8 = __attribute__((ext_vector_type(8))) short;
using f32x4  = __attribute__((ext_vector_type(4))) float;

__device__ inline unsigned short f2b(float f) {
    return __builtin_bit_cast(unsigned short, __float2bfloat16(f));
}
__device__ inline unsigned pk2(float a, float b) {
    return (unsigned)f2b(a) | ((unsigned)f2b(b) << 16);
}
__device__ inline float blo(unsigned v) { return __builtin_bit_cast(float, v << 16); }
__device__ inline float bhi(unsigned v) { return __builtin_bit_cast(float, v & 0xffff0000u); }
__device__ inline float clip1(float v) { return fminf(fmaxf(v, -1.f), 1.f); }

// ---------------------------------------------------------------------------
// P0: convert K,Q -> bf16 (Kb, Qb) and build u_t[bt][x*16+c] = x[bt][c][x]
// ---------------------------------------------------------------------------
__global__ void prep_kernel(const float* __restrict__ K, const float* __restrict__ Q,
                            const float* __restrict__ xin,
                            unsigned short* __restrict__ Kb, unsigned short* __restrict__ Qb,
                            float* __restrict__ u_t)
{
    int b = blockIdx.x, t = threadIdx.x;
    if (b < 2048) {
        bool isK = (b < 1024);
        int bb = isK ? b : b - 1024;
        int i = bb * 1024 + t * 4;
        const float4 f = ((const float4*)(isK ? K : Q))[i >> 2];
        short4 v;
        v.x = (short)f2b(f.x); v.y = (short)f2b(f.y);
        v.z = (short)f2b(f.z); v.w = (short)f2b(f.w);
        *(short4*)((isK ? Kb : Qb) + i) = v;
    } else {
        int bt = b - 2048;                    // 0..47
        const float* src = xin + (size_t)bt * 4096;
        float* dst = u_t + (size_t)bt * 4096;
        int xx = t;                           // 0..255
        #pragma unroll
        for (int c = 0; c < 16; ++c)
            dst[xx * 16 + c] = src[c * 256 + xx];
    }
}

// ---------------------------------------------------------------------------
// W2[X][n] = sum_x w[x] * clip(Aon[X,x,n]) ;  grid 256 x 128
// ---------------------------------------------------------------------------
__global__ void w2_kernel(const float* __restrict__ Aon, const float* __restrict__ wv,
                          float* __restrict__ W2)
{
    int X = blockIdx.x, n = threadIdx.x;
    if (n >= 100) return;
    const float* base = Aon + (size_t)X * 25600 + n;
    float acc = 0.f;
    for (int b = 0; b < 256; ++b)
        acc += wv[b] * clip1(base[(size_t)b * 100]);
    W2[X * 100 + n] = acc;
}

// ---------------------------------------------------------------------------
// kvt[bt][X][Y] = sum_j Kb[X,j]*u[j] * Qb[Y,j]   (bf16 MFMA, fp32 acc)
// grid 192 (= 48 bt * 4 tiles of 128x128), block 256 (4 waves, each 64x64)
// ---------------------------------------------------------------------------
__global__ __launch_bounds__(256) void gemm_kvt(const unsigned short* __restrict__ Kb,
                                                const unsigned short* __restrict__ Qb,
                                                const float* __restrict__ u_t,
                                                float* __restrict__ kvt)
{
    int bt   = blockIdx.x >> 2;
    int tile = blockIdx.x & 3;
    int Xb = (tile >> 1) * 128, Yb = (tile & 1) * 128;

    __shared__ float u_s[4096];                 // 16 KB
    __shared__ unsigned short As[128][40];      // padded stride 40 (80B)
    __shared__ unsigned short Bs[128][40];

    int tid = threadIdx.x;
    {
        const float4* us = (const float4*)(u_t + (size_t)bt * 4096);
        float4* ud = (float4*)u_s;
        for (int i = tid; i < 1024; i += 256) ud[i] = us[i];
    }
    __syncthreads();

    int wave = tid >> 6, lane = tid & 63;
    int wr = (wave >> 1) * 64, wc = (wave & 1) * 64;
    int lrow = lane & 15, kg = lane >> 4;

    f32x4 zero = {0.f, 0.f, 0.f, 0.f};
    f32x4 acc[4][4];
    #pragma unroll
    for (int m = 0; m < 4; ++m)
        #pragma unroll
        for (int n = 0; n < 4; ++n) acc[m][n] = zero;

    int r = tid >> 1, half = tid & 1;

    for (int kk = 0; kk < 128; ++kk) {
        int k0 = kk * 32;
        int j0 = k0 + half * 16;
        // ---- stage A = Kb * u  (16 bf16 per thread) ----
        const uint4* ka = (const uint4*)(Kb + (size_t)(Xb + r) * 4096 + j0);
        uint4 kv0 = ka[0], kv1 = ka[1];
        float4 u0 = *(const float4*)(u_s + j0);
        float4 u1 = *(const float4*)(u_s + j0 + 4);
        float4 u2 = *(const float4*)(u_s + j0 + 8);
        float4 u3 = *(const float4*)(u_s + j0 + 12);
        uint4 o0, o1;
        o0.x = pk2(blo(kv0.x) * u0.x, bhi(kv0.x) * u0.y);
        o0.y = pk2(blo(kv0.y) * u0.z, bhi(kv0.y) * u0.w);
        o0.z = pk2(blo(kv0.z) * u1.x, bhi(kv0.z) * u1.y);
        o0.w = pk2(blo(kv0.w) * u1.z, bhi(kv0.w) * u1.w);
        o1.x = pk2(blo(kv1.x) * u2.x, bhi(kv1.x) * u2.y);
        o1.y = pk2(blo(kv1.y) * u2.z, bhi(kv1.y) * u2.w);
        o1.z = pk2(blo(kv1.z) * u3.x, bhi(kv1.z) * u3.y);
        o1.w = pk2(blo(kv1.w) * u3.z, bhi(kv1.w) * u3.w);
        *(uint4*)&As[r][half * 16]     = o0;
        *(uint4*)&As[r][half * 16 + 8] = o1;
        // ---- stage B = Qb (raw bf16 copy) ----
        const uint4* qa = (const uint4*)(Qb + (size_t)(Yb + r) * 4096 + j0);
        uint4 q0 = qa[0], q1 = qa[1];
        *(uint4*)&Bs[r][half * 16]     = q0;
        *(uint4*)&Bs[r][half * 16 + 8] = q1;
        __syncthreads();

        short8 af[4], bf_[4];
        #pragma unroll
        for (int m = 0; m < 4; ++m)
            af[m] = *(const short8*)&As[wr + m * 16 + lrow][kg * 8];
        #pragma unroll
        for (int n = 0; n < 4; ++n)
            bf_[n] = *(const short8*)&Bs[wc + n * 16 + lrow][kg * 8];
        #pragma unroll
        for (int m = 0; m < 4; ++m)
            #pragma unroll
            for (int n = 0; n < 4; ++n)
                acc[m][n] = __builtin_amdgcn_mfma_f32_16x16x32_bf16(af[m], bf_[n], acc[m][n], 0, 0, 0);
        __syncthreads();
    }

    float* outp = kvt + (size_t)bt * 65536;
    int row0 = Xb + wr + kg * 4;
    int col0 = Yb + wc + lrow;
    #pragma unroll
    for (int m = 0; m < 4; ++m)
        #pragma unroll
        for (int n = 0; n < 4; ++n)
            #pragma unroll
            for (int rr = 0; rr < 4; ++rr)
                outp[(size_t)(row0 + m * 16 + rr) * 256 + col0 + n * 16] = acc[m][n][rr];
}

// ---------------------------------------------------------------------------
// Sp[cb][bp][J][n] = sum_{k in chunk cb (128 wide)} clip(Ano[k][n]) * kvt[bp*12+J][k]
// grid 512, block 256 (wave = bp). Both operands staged in LDS; k unrolled x4,
// kvt rows read as uniform ds_read_b128 broadcasts.
// ---------------------------------------------------------------------------
__global__ __launch_bounds__(256) void s_partial(const float* __restrict__ Ano,
                                                 const float* __restrict__ kvt,
                                                 float* __restrict__ Sp)
{
    __shared__ float ano_f[12864];          // 128*100 + 64 pad  (51.5 KB)
    __shared__ float kvt_s[44][128];        // 22.5 KB
    int cb = blockIdx.x;
    int k0 = cb * 128;
    int tid = threadIdx.x;

    {   // stage Ano chunk, clipped (12800 floats = 3200 float4)
        const float4* src = (const float4*)(Ano + (size_t)k0 * 100);
        float4* dst = (float4*)ano_f;
        for (int i = tid; i < 3200; i += 256) {
            float4 f = src[i];
            f.x = clip1(f.x); f.y = clip1(f.y); f.z = clip1(f.z); f.w = clip1(f.w);
            dst[i] = f;
        }
    }
    {   // stage kvt rows r=bp*11+J -> kvt row bp*12+J, 44 rows x 128 k
        for (int idx = tid; idx < 5632; idx += 256) {
            int r = idx >> 7, k = idx & 127;
            int bpr = r / 11, Jr = r - bpr * 11;
            kvt_s[r][k] = kvt[(size_t)(bpr * 12 + Jr) * 65536 + k0 + k];
        }
    }
    __syncthreads();

    int lane = tid & 63;
    int bp = tid >> 6;
    bool has2 = lane < 36;
    float acc0[11], acc1[11];
    #pragma unroll
    for (int J = 0; J < 11; ++J) { acc0[J] = 0.f; acc1[J] = 0.f; }

    for (int k = 0; k < 128; k += 4) {
        f32x4 kv[11];
        #pragma unroll
        for (int J = 0; J < 11; ++J)
            kv[J] = *(const f32x4*)&kvt_s[bp * 11 + J][k];
        #pragma unroll
        for (int kk = 0; kk < 4; ++kk) {
            float a0 = ano_f[(k + kk) * 100 + lane];
            float a1r = ano_f[(k + kk) * 100 + 64 + lane];   // padded, in-bounds
            float a1 = has2 ? a1r : 0.f;
            #pragma unroll
            for (int J = 0; J < 11; ++J) {
                acc0[J] += kv[J][kk] * a0;
                acc1[J] += kv[J][kk] * a1;
            }
        }
    }
    float* outb = Sp + ((size_t)cb * 4 + bp) * 1100;
    #pragma unroll
    for (int J = 0; J < 11; ++J) {
        outb[J * 100 + lane] = acc0[J];
        if (has2) outb[J * 100 + 64 + lane] = acc1[J];
    }
}

// S[bp*11+J][n] = sum_cb Sp[cb][bp][J][n] ; grid 44 x 128
__global__ void reduce_s(const float* __restrict__ Sp, float* __restrict__ S)
{
    int bp = blockIdx.x / 11, J = blockIdx.x % 11;
    int t = threadIdx.x;
    if (t >= 100) return;
    float acc = 0.f;
    for (int c = 0; c < 512; ++c)
        acc += Sp[((size_t)c * 4 + bp) * 1100 + J * 100 + t];
    S[(bp * 11 + J) * 100 + t] = acc;
}

// c2[bp][n] = S[bp][10][n] + sum_J A_seq[9-J][n] * S[bp][J][n] ; 1 x 512
__global__ void c2_kernel(const float* __restrict__ S, const float* __restrict__ Ann,
                          float* __restrict__ c2)
{
    int t = threadIdx.x;
    int bp = t >> 7, n = t & 127;
    if (n >= 100) return;
    float a = Ann[n];
    float seq[10];
    float v = a;
    seq[0] = v;
    #pragma unroll
    for (int s = 1; s < 10; ++s) { v = clip1(v * a); seq[s] = v; }
    float r = S[(bp * 11 + 10) * 100 + n];
    #pragma unroll
    for (int J = 0; J < 10; ++J)
        r += seq[9 - J] * S[(bp * 11 + J) * 100 + n];
    c2[bp * 100 + n] = r;
}

// hw[bp][X] = sum_x w[x]*Aoo[X,x]*kvt11[X,x] + sum_n c2[bp][n]*W2[X][n]
__global__ __launch_bounds__(256) void hw_kernel(const float* __restrict__ Aoo,
                                                 const float* __restrict__ wv,
                                                 const float* __restrict__ kvt,
                                                 const float* __restrict__ W2,
                                                 const float* __restrict__ c2,
                                                 float* __restrict__ hw)
{
    int bp = blockIdx.x >> 6, Xg = blockIdx.x & 63;
    int wave = threadIdx.x >> 6, lane = threadIdx.x & 63;
    int X = Xg * 4 + wave;
    const float* kv = kvt + ((size_t)bp * 12 + 11) * 65536 + (size_t)X * 256;
    const float* ao = Aoo + (size_t)X * 256;
    float red = 0.f;
    #pragma unroll
    for (int q = 0; q < 4; ++q) {
        int xx = q * 64 + lane;
        red += wv[xx] * ao[xx] * kv[xx];
    }
    red += c2[bp * 100 + lane] * W2[X * 100 + lane];
    if (lane < 36)
        red += c2[bp * 100 + 64 + lane] * W2[X * 100 + 64 + lane];
    #pragma unroll
    for (int off = 32; off; off >>= 1) red += __shfl_xor(red, off);
    if (lane == 0) hw[bp * 256 + X] = red;
}

// vh[bp][j] = sum_X hw[bp][X] * V[X][j] ; grid 16 x 256
__global__ __launch_bounds__(256) void vh_kernel(const float* __restrict__ V,
                                                 const float* __restrict__ hw,
                                                 float* __restrict__ vh)
{
    int bp = blockIdx.x >> 2, jg = blockIdx.x & 3;
    int t = threadIdx.x;
    float a0 = 0.f, a1 = 0.f, a2 = 0.f, a3 = 0.f;
    const float* hb = hw + bp * 256;
    const float* vb = V + jg * 1024 + t;
    for (int X = 0; X < 256; ++X) {
        float h = hb[X];
        const float* vr = vb + (size_t)X * 4096;
        a0 += h * vr[0];
        a1 += h * vr[256];
        a2 += h * vr[512];
        a3 += h * vr[768];
    }
    float* o = vh + bp * 4096 + jg * 1024 + t;
    o[0] = a0; o[256] = a1; o[512] = a2; o[768] = a3;
}

// y[bp*16+c] = sum_x xlast[bp][c][x] * vh[bp][x*16+c] ; 1 x 64
__global__ void y_kernel(const float* __restrict__ xin, const float* __restrict__ vh,
                         float* __restrict__ out)
{
    int t = threadIdx.x;
    if (t >= 64) return;
    int bp = t >> 4, c = t & 15;
    const float* xl = xin + ((size_t)bp * 12 + 11) * 4096 + c * 256;
    const float* vb = vh + bp * 4096 + c;
    float acc = 0.f;
    for (int xx = 0; xx < 256; ++xx)
        acc += xl[xx] * vb[xx * 16];
    out[t] = acc;
}

// ---------------------------------------------------------------------------
extern "C" void kernel_launch(void* const* d_in, const int* in_sizes, int n_in,
                              void* d_out, int out_size, void* d_ws, size_t ws_size,
                              hipStream_t stream)
{
    const float* x   = (const float*)d_in[0];
    const float* K   = (const float*)d_in[1];
    const float* Q   = (const float*)d_in[2];
    const float* V   = (const float*)d_in[3];
    const float* Aoo = (const float*)d_in[4];
    const float* Ann = (const float*)d_in[5];
    const float* Aon = (const float*)d_in[6];
    const float* Ano = (const float*)d_in[7];
    const float* wv  = (const float*)d_in[8];
    float* out = (float*)d_out;

    char* ws = (char*)d_ws;
    const size_t o_Qb  = 0;
    const size_t o_Kb  = o_Qb  + (size_t)2  * 1024 * 1024;
    const size_t o_ut  = o_Kb  + (size_t)2  * 1024 * 1024;
    const size_t o_kvt = o_ut  + (size_t)48 * 4096 * 4;
    const size_t o_Sp  = o_kvt + (size_t)48 * 65536 * 4;
    const size_t o_S   = o_Sp  + (size_t)512 * 4400 * 4;
    const size_t o_c2  = o_S   + (size_t)4400 * 4;
    const size_t o_W2  = o_c2  + (size_t)400 * 4 + 16;
    const size_t o_hw  = o_W2  + (size_t)25600 * 4;
    const size_t o_vh  = o_hw  + (size_t)1024 * 4;

    unsigned short* Kb = (unsigned short*)(ws + o_Kb);
    unsigned short* Qb = (unsigned short*)(ws + o_Qb);
    float* u_t = (float*)(ws + o_ut);
    float* kvt = (float*)(ws + o_kvt);
    float* Sp  = (float*)(ws + o_Sp);
    float* S   = (float*)(ws + o_S);
    float* c2  = (float*)(ws + o_c2);
    float* W2  = (float*)(ws + o_W2);
    float* hw  = (float*)(ws + o_hw);
    float* vh  = (float*)(ws + o_vh);

    hipLaunchKernelGGL(prep_kernel, dim3(2096), dim3(256), 0, stream, K, Q, x, Kb, Qb, u_t);
    hipLaunchKernelGGL(w2_kernel,   dim3(256),  dim3(128), 0, stream, Aon, wv, W2);
    hipLaunchKernelGGL(gemm_kvt,    dim3(192),  dim3(256), 0, stream, Kb, Qb, u_t, kvt);
    hipLaunchKernelGGL(s_partial,   dim3(512),  dim3(256), 0, stream, Ano, kvt, Sp);
    hipLaunchKernelGGL(reduce_s,    dim3(44),   dim3(128), 0, stream, Sp, S);
    hipLaunchKernelGGL(c2_kernel,   dim3(1),    dim3(512), 0, stream, S, Ann, c2);
    hipLaunchKernelGGL(hw_kernel,   dim3(256),  dim3(256), 0, stream, Aoo, wv, kvt, W2, c2, hw);
    hipLaunchKernelGGL(vh_kernel,   dim3(16),   dim3(256), 0, stream, V, hw, vh);
    hipLaunchKernelGGL(y_kernel,    dim3(1),    dim3(64),  0, stream, x, vh, out);
}

// Round 3
// 247.535 us; speedup vs baseline: 1.7321x; 1.0034x over previous
//
#include <hip/hip_runtime.h>
#include <hip/hip_fp16.h>

// ---------------------------------------------------------------------------
// NL=16, NS=256, NE=100, B=2, P=2, T=12
// x:(2,2,12,16,256) K/Q/V:(256,256,16) Aoo:(256,256) Ann:(100,)
// Aon/Ano:(256,256,100) w:(256,)  out:(2,2,1,16)=64 fp32
// kvt[bt][X][Y] = sum_j Kh[X,j]*u[bt,j]*Qh[Y,j],  j = x*16+c  (K=4096)
// ---------------------------------------------------------------------------

using f32x4 = __attribute__((ext_vector_type(4))) float;
using half8 = __attribute__((ext_vector_type(8))) _Float16;
using half4 = __attribute__((ext_vector_type(4))) _Float16;

#define KVT_STRIDE 3145728ull    // 48*65536 floats per K-chunk partial

__device__ inline float clip1(float v) { return fminf(fmaxf(v, -1.f), 1.f); }

__device__ inline half8 mul8(uint4 a, uint4 b) {
    half8 x = __builtin_bit_cast(half8, a);
    half8 y = __builtin_bit_cast(half8, b);
    return x * y;                          // v_pk_mul_f16 x4
}

// ---------------------------------------------------------------------------
// P0: K,Q -> fp16 ; u_t[bt][x*16+c] = (fp16) x[bt][c][x]
// ---------------------------------------------------------------------------
__global__ void prep_kernel(const float* __restrict__ K, const float* __restrict__ Q,
                            const float* __restrict__ xin,
                            __half* __restrict__ Kh, __half* __restrict__ Qh,
                            __half* __restrict__ u_t)
{
    int b = blockIdx.x, t = threadIdx.x;
    if (b < 2048) {
        bool isK = (b < 1024);
        int bb = isK ? b : b - 1024;
        int i = bb * 1024 + t * 4;
        const float4 f = ((const float4*)(isK ? K : Q))[i >> 2];
        half4 v = { (_Float16)f.x, (_Float16)f.y, (_Float16)f.z, (_Float16)f.w };
        *(half4*)((isK ? Kh : Qh) + i) = v;
    } else {
        int bt = b - 2048;                    // 0..47
        const float* src = xin + (size_t)bt * 4096;
        int xx = t;                           // 0..255
        half8 lo, hi;
        #pragma unroll
        for (int c = 0; c < 8; ++c)  lo[c] = (_Float16)src[c * 256 + xx];
        #pragma unroll
        for (int c = 0; c < 8; ++c)  hi[c] = (_Float16)src[(c + 8) * 256 + xx];
        half8* dst = (half8*)(u_t + (size_t)bt * 4096 + xx * 16);
        dst[0] = lo; dst[1] = hi;
    }
}

// ---------------------------------------------------------------------------
// W2[X][n] = sum_x w[x] * clip(Aon[X,x,n]) ;  grid 256 x 128
// ---------------------------------------------------------------------------
__global__ void w2_kernel(const float* __restrict__ Aon, const float* __restrict__ wv,
                          float* __restrict__ W2)
{
    int X = blockIdx.x, n = threadIdx.x;
    if (n >= 100) return;
    const float* base = Aon + (size_t)X * 25600 + n;
    float acc = 0.f;
    for (int b = 0; b < 256; ++b)
        acc += wv[b] * clip1(base[(size_t)b * 100]);
    W2[X * 100 + n] = acc;
}

// ---------------------------------------------------------------------------
// GEMM, direct global->register fragments, no barriers in K-loop.
// grid = 192*KS (XCD-swizzled), block 256 = 4 waves, each wave owns a 64x64
// quadrant of a 128x128 tile; block covers K-chunk kc (Kc = 4096/KS).
// Writes fp32 partial to kvtp[kc].
// ---------------------------------------------------------------------------
__global__ __launch_bounds__(256, 3) void gemm_kvt(
    const __half* __restrict__ Kh, const __half* __restrict__ Qh,
    const __half* __restrict__ u_t, float* __restrict__ kvtp,
    int KS, int q)
{
    int bid = blockIdx.x;
    int work = (bid & 7) * q + (bid >> 3);     // XCD-contiguous work ids
    int perbt = KS << 2;
    int bt = work / perbt;
    int rem = work - bt * perbt;
    int tile = rem / KS;                        // 0..3
    int kc = rem - tile * KS;                   // 0..KS-1
    int Kc = 4096 / KS;
    int nsteps = Kc >> 6;                       // BK = 64
    int kbase = kc * Kc;
    int Xb = (tile >> 1) * 128, Yb = (tile & 1) * 128;

    __shared__ __half uh_s[2048];               // K-chunk of u (<= 2048 when KS>=2)
    int tid = threadIdx.x;
    if (KS == 1) {                              // fallback: stage 4096 in two rounds
        *(uint4*)&uh_s[0];                      // (no-op ref)
    }
    if (tid < (Kc >> 3) && Kc <= 2048)
        *(uint4*)&uh_s[tid * 8] = *(const uint4*)(u_t + (size_t)bt * 4096 + kbase + tid * 8);
    __syncthreads();

    int wave = tid >> 6, lane = tid & 63;
    int wr = (wave >> 1) * 64, wc = (wave & 1) * 64;
    int lrow = lane & 15, kg = lane >> 4;

    const __half* Ap[4];
    const __half* Bp[4];
    #pragma unroll
    for (int m = 0; m < 4; ++m)
        Ap[m] = Kh + (size_t)(Xb + wr + m * 16 + lrow) * 4096 + kbase + kg * 8;
    #pragma unroll
    for (int n = 0; n < 4; ++n)
        Bp[n] = Qh + (size_t)(Yb + wc + n * 16 + lrow) * 4096 + kbase + kg * 8;
    const __half* upg = u_t + (size_t)bt * 4096 + kbase + kg * 8;  // for KS==1 path
    const __half* upl = uh_s + kg * 8;

    f32x4 acc[4][4];
    f32x4 zero = {0.f, 0.f, 0.f, 0.f};
    #pragma unroll
    for (int m = 0; m < 4; ++m)
        #pragma unroll
        for (int n = 0; n < 4; ++n) acc[m][n] = zero;

    bool useLds = (Kc <= 2048);

    for (int s = 0; s < nsteps; ++s) {
        #pragma unroll
        for (int kh = 0; kh < 2; ++kh) {
            uint4 uv = useLds ? *(const uint4*)(upl + kh * 32)
                              : *(const uint4*)(upg + kh * 32);
            half8 af[4], bf[4];
            #pragma unroll
            for (int m = 0; m < 4; ++m) {
                uint4 kv = *(const uint4*)(Ap[m] + kh * 32);
                af[m] = mul8(kv, uv);
            }
            #pragma unroll
            for (int n = 0; n < 4; ++n)
                bf[n] = *(const half8*)(Bp[n] + kh * 32);
            #pragma unroll
            for (int m = 0; m < 4; ++m)
                #pragma unroll
                for (int n = 0; n < 4; ++n)
                    acc[m][n] = __builtin_amdgcn_mfma_f32_16x16x32_f16(af[m], bf[n], acc[m][n], 0, 0, 0);
        }
        #pragma unroll
        for (int m = 0; m < 4; ++m) Ap[m] += 64;
        #pragma unroll
        for (int n = 0; n < 4; ++n) Bp[n] += 64;
        upl += 64; upg += 64;
    }

    // epilogue: D layout col = lane&15, row = (lane>>4)*4 + reg
    float* outp = kvtp + (size_t)kc * KVT_STRIDE + (size_t)bt * 65536;
    int row0 = Xb + wr + kg * 4;
    int col0 = Yb + wc + lrow;
    #pragma unroll
    for (int m = 0; m < 4; ++m)
        #pragma unroll
        for (int n = 0; n < 4; ++n)
            #pragma unroll
            for (int rr = 0; rr < 4; ++rr)
                outp[(size_t)(row0 + m * 16 + rr) * 256 + col0 + n * 16] = acc[m][n][rr];
}

// ---------------------------------------------------------------------------
// Sp[cb][bp][J][n] = sum_{k in 128-chunk cb} clip(Ano[k][n]) * kvt[bp*12+J][k]
// kvt materialized on the fly as sum of KS partials (L3-resident).
// ---------------------------------------------------------------------------
__global__ __launch_bounds__(256) void s_partial(const float* __restrict__ Ano,
                                                 const float* __restrict__ kvtp,
                                                 float* __restrict__ Sp, int KS)
{
    __shared__ float ano_f[12864];          // 128*100 + pad
    __shared__ float kvt_s[44][128];
    int cb = blockIdx.x;
    int k0 = cb * 128;
    int tid = threadIdx.x;

    {
        const float4* src = (const float4*)(Ano + (size_t)k0 * 100);
        float4* dst = (float4*)ano_f;
        for (int i = tid; i < 3200; i += 256) {
            float4 f = src[i];
            f.x = clip1(f.x); f.y = clip1(f.y); f.z = clip1(f.z); f.w = clip1(f.w);
            dst[i] = f;
        }
    }
    {
        for (int idx = tid; idx < 5632; idx += 256) {
            int rI = idx >> 7, k = idx & 127;
            int bpr = rI / 11, Jr = rI - bpr * 11;
            size_t off = (size_t)(bpr * 12 + Jr) * 65536 + k0 + k;
            float v = 0.f;
            for (int c = 0; c < KS; ++c) v += kvtp[(size_t)c * KVT_STRIDE + off];
            kvt_s[rI][k] = v;
        }
    }
    __syncthreads();

    int lane = tid & 63;
    int bp = tid >> 6;
    bool has2 = lane < 36;
    float acc0[11], acc1[11];
    #pragma unroll
    for (int J = 0; J < 11; ++J) { acc0[J] = 0.f; acc1[J] = 0.f; }

    for (int k = 0; k < 128; k += 4) {
        f32x4 kv[11];
        #pragma unroll
        for (int J = 0; J < 11; ++J)
            kv[J] = *(const f32x4*)&kvt_s[bp * 11 + J][k];
        #pragma unroll
        for (int kk = 0; kk < 4; ++kk) {
            float a0 = ano_f[(k + kk) * 100 + lane];
            float a1r = ano_f[(k + kk) * 100 + 64 + lane];
            float a1 = has2 ? a1r : 0.f;
            #pragma unroll
            for (int J = 0; J < 11; ++J) {
                acc0[J] += kv[J][kk] * a0;
                acc1[J] += kv[J][kk] * a1;
            }
        }
    }
    float* outb = Sp + ((size_t)cb * 4 + bp) * 1100;
    #pragma unroll
    for (int J = 0; J < 11; ++J) {
        outb[J * 100 + lane] = acc0[J];
        if (has2) outb[J * 100 + 64 + lane] = acc1[J];
    }
}

// S[bp*11+J][n] = sum_cb Sp[cb][bp][J][n] ; grid 44 x 128
__global__ void reduce_s(const float* __restrict__ Sp, float* __restrict__ S)
{
    int bp = blockIdx.x / 11, J = blockIdx.x % 11;
    int t = threadIdx.x;
    if (t >= 100) return;
    float acc = 0.f;
    for (int c = 0; c < 512; ++c)
        acc += Sp[((size_t)c * 4 + bp) * 1100 + J * 100 + t];
    S[(bp * 11 + J) * 100 + t] = acc;
}

// c2[bp][n] = S[bp][10][n] + sum_J A_seq[9-J][n] * S[bp][J][n] ; 1 x 512
__global__ void c2_kernel(const float* __restrict__ S, const float* __restrict__ Ann,
                          float* __restrict__ c2)
{
    int t = threadIdx.x;
    int bp = t >> 7, n = t & 127;
    if (n >= 100) return;
    float a = Ann[n];
    float seq[10];
    float v = a;
    seq[0] = v;
    #pragma unroll
    for (int s = 1; s < 10; ++s) { v = clip1(v * a); seq[s] = v; }
    float r = S[(bp * 11 + 10) * 100 + n];
    #pragma unroll
    for (int J = 0; J < 10; ++J)
        r += seq[9 - J] * S[(bp * 11 + J) * 100 + n];
    c2[bp * 100 + n] = r;
}

// hw[bp][X] = sum_x w[x]*Aoo[X,x]*kvt11[X,x] + sum_n c2[bp][n]*W2[X][n]
__global__ __launch_bounds__(256) void hw_kernel(const float* __restrict__ Aoo,
                                                 const float* __restrict__ wv,
                                                 const float* __restrict__ kvtp,
                                                 const float* __restrict__ W2,
                                                 const float* __restrict__ c2,
                                                 float* __restrict__ hw, int KS)
{
    int bp = blockIdx.x >> 6, Xg = blockIdx.x & 63;
    int wave = threadIdx.x >> 6, lane = threadIdx.x & 63;
    int X = Xg * 4 + wave;
    size_t base = (size_t)(bp * 12 + 11) * 65536 + (size_t)X * 256;
    const float* ao = Aoo + (size_t)X * 256;
    float red = 0.f;
    #pragma unroll
    for (int qq = 0; qq < 4; ++qq) {
        int xx = qq * 64 + lane;
        float kvv = 0.f;
        for (int c = 0; c < KS; ++c) kvv += kvtp[(size_t)c * KVT_STRIDE + base + xx];
        red += wv[xx] * ao[xx] * kvv;
    }
    red += c2[bp * 100 + lane] * W2[X * 100 + lane];
    if (lane < 36)
        red += c2[bp * 100 + 64 + lane] * W2[X * 100 + 64 + lane];
    #pragma unroll
    for (int off = 32; off; off >>= 1) red += __shfl_xor(red, off);
    if (lane == 0) hw[bp * 256 + X] = red;
}

// vh[bp][j] = sum_X hw[bp][X] * V[X][j] ; grid 16 x 256
__global__ __launch_bounds__(256) void vh_kernel(const float* __restrict__ V,
                                                 const float* __restrict__ hw,
                                                 float* __restrict__ vh)
{
    int bp = blockIdx.x >> 2, jg = blockIdx.x & 3;
    int t = threadIdx.x;
    float a0 = 0.f, a1 = 0.f, a2 = 0.f, a3 = 0.f;
    const float* hb = hw + bp * 256;
    const float* vb = V + jg * 1024 + t;
    for (int X = 0; X < 256; ++X) {
        float h = hb[X];
        const float* vr = vb + (size_t)X * 4096;
        a0 += h * vr[0];
        a1 += h * vr[256];
        a2 += h * vr[512];
        a3 += h * vr[768];
    }
    float* o = vh + bp * 4096 + jg * 1024 + t;
    o[0] = a0; o[256] = a1; o[512] = a2; o[768] = a3;
}

// y[bp*16+c] = sum_x xlast[bp][c][x] * vh[bp][x*16+c] ; 1 x 64
__global__ void y_kernel(const float* __restrict__ xin, const float* __restrict__ vh,
                         float* __restrict__ out)
{
    int t = threadIdx.x;
    if (t >= 64) return;
    int bp = t >> 4, c = t & 15;
    const float* xl = xin + ((size_t)bp * 12 + 11) * 4096 + c * 256;
    const float* vb = vh + bp * 4096 + c;
    float acc = 0.f;
    for (int xx = 0; xx < 256; ++xx)
        acc += xl[xx] * vb[xx * 16];
    out[t] = acc;
}

// ---------------------------------------------------------------------------
extern "C" void kernel_launch(void* const* d_in, const int* in_sizes, int n_in,
                              void* d_out, int out_size, void* d_ws, size_t ws_size,
                              hipStream_t stream)
{
    const float* x   = (const float*)d_in[0];
    const float* K   = (const float*)d_in[1];
    const float* Q   = (const float*)d_in[2];
    const float* V   = (const float*)d_in[3];
    const float* Aoo = (const float*)d_in[4];
    const float* Ann = (const float*)d_in[5];
    const float* Aon = (const float*)d_in[6];
    const float* Ano = (const float*)d_in[7];
    const float* wv  = (const float*)d_in[8];
    float* out = (float*)d_out;

    char* ws = (char*)d_ws;
    const size_t o_Qh   = 0;                                  // 2 MB
    const size_t o_Kh   = o_Qh + (size_t)2 * 1024 * 1024;     // 2 MB
    const size_t o_ut   = o_Kh + (size_t)2 * 1024 * 1024;     // 384 KB (pad .5 MB)
    const size_t o_kvtp = o_ut + (size_t)512 * 1024;

    // choose K-split factor so partials fit ws
    auto needed = [&](int ks) {
        size_t p = o_kvtp + (size_t)ks * KVT_STRIDE * 4;      // partials
        p += (size_t)512 * 4400 * 4;                          // Sp
        p += 4400 * 4 + 400 * 4 + 64 + 25600 * 4 + 1024 * 4 + 16384 * 4;
        return p + 4096;
    };
    int KS = 4;
    if (ws_size < needed(4)) KS = 2;
    if (ws_size < needed(2)) KS = 1;

    const size_t o_Sp  = o_kvtp + (size_t)KS * KVT_STRIDE * 4;
    const size_t o_S   = o_Sp + (size_t)512 * 4400 * 4;
    const size_t o_c2  = o_S + 4400 * 4;
    const size_t o_W2  = o_c2 + 400 * 4 + 64;
    const size_t o_hw  = o_W2 + 25600 * 4;
    const size_t o_vh  = o_hw + 1024 * 4;

    __half* Qh  = (__half*)(ws + o_Qh);
    __half* Kh  = (__half*)(ws + o_Kh);
    __half* u_t = (__half*)(ws + o_ut);
    float* kvtp = (float*)(ws + o_kvtp);
    float* Sp   = (float*)(ws + o_Sp);
    float* S    = (float*)(ws + o_S);
    float* c2   = (float*)(ws + o_c2);
    float* W2   = (float*)(ws + o_W2);
    float* hw   = (float*)(ws + o_hw);
    float* vh   = (float*)(ws + o_vh);

    int nwg = 192 * KS;
    int q = nwg / 8;

    hipLaunchKernelGGL(prep_kernel, dim3(2096), dim3(256), 0, stream, K, Q, x, Kh, Qh, u_t);
    hipLaunchKernelGGL(w2_kernel,   dim3(256),  dim3(128), 0, stream, Aon, wv, W2);
    hipLaunchKernelGGL(gemm_kvt,    dim3(nwg),  dim3(256), 0, stream, Kh, Qh, u_t, kvtp, KS, q);
    hipLaunchKernelGGL(s_partial,   dim3(512),  dim3(256), 0, stream, Ano, kvtp, Sp, KS);
    hipLaunchKernelGGL(reduce_s,    dim3(44),   dim3(128), 0, stream, Sp, S);
    hipLaunchKernelGGL(c2_kernel,   dim3(1),    dim3(512), 0, stream, S, Ann, c2);
    hipLaunchKernelGGL(hw_kernel,   dim3(256),  dim3(256), 0, stream, Aoo, wv, kvtp, W2, c2, hw, KS);
    hipLaunchKernelGGL(vh_kernel,   dim3(16),   dim3(256), 0, stream, V, hw, vh);
    hipLaunchKernelGGL(y_kernel,    dim3(1),    dim3(64),  0, stream, x, vh, out);
}

// Round 4
// 112.324 us; speedup vs baseline: 3.8172x; 2.2038x over previous
//
#include <hip/hip_runtime.h>
#include <hip/hip_fp16.h>

// ---------------------------------------------------------------------------
// NL=16, NS=256, NE=100, B=2, P=2, T=12
// x:(2,2,12,16,256) K/Q/V:(256,256,16) Aoo:(256,256) Ann:(100,)
// Aon/Ano:(256,256,100) w:(256,)  out:(2,2,1,16)=64 fp32
// kvt[bt][X][Y] = sum_j Kh[X,j]*u[bt,j]*Qh[Y,j],  j = x*16+c  (K=4096)
// ---------------------------------------------------------------------------

using f32x4 = __attribute__((ext_vector_type(4))) float;
using half8 = __attribute__((ext_vector_type(8))) _Float16;
using half4 = __attribute__((ext_vector_type(4))) _Float16;

#define KVT_STRIDE 3145728ull    // 48*65536 floats per K-chunk partial
#define KS 4

__device__ inline float clip1(float v) { return fminf(fmaxf(v, -1.f), 1.f); }

__device__ inline half8 mul8(uint4 a, uint4 b) {
    half8 x = __builtin_bit_cast(half8, a);
    half8 y = __builtin_bit_cast(half8, b);
    return x * y;                          // v_pk_mul_f16 x4
}

__device__ __forceinline__ void gl_lds16(const void* g, void* l) {
    __builtin_amdgcn_global_load_lds(
        (const __attribute__((address_space(1))) void*)g,
        (__attribute__((address_space(3))) void*)l, 16, 0, 0);
}

// ---------------------------------------------------------------------------
// P0: K,Q -> fp16 ; u_t[bt][x*16+c] = (fp16) x[bt][c][x]
// ---------------------------------------------------------------------------
__global__ void prep_kernel(const float* __restrict__ K, const float* __restrict__ Q,
                            const float* __restrict__ xin,
                            __half* __restrict__ Kh, __half* __restrict__ Qh,
                            __half* __restrict__ u_t)
{
    int b = blockIdx.x, t = threadIdx.x;
    if (b < 2048) {
        bool isK = (b < 1024);
        int bb = isK ? b : b - 1024;
        int i = bb * 1024 + t * 4;
        const float4 f = ((const float4*)(isK ? K : Q))[i >> 2];
        half4 v = { (_Float16)f.x, (_Float16)f.y, (_Float16)f.z, (_Float16)f.w };
        *(half4*)((isK ? Kh : Qh) + i) = v;
    } else {
        int bt = b - 2048;                    // 0..47
        const float* src = xin + (size_t)bt * 4096;
        int xx = t;                           // 0..255
        half8 lo, hi;
        #pragma unroll
        for (int c = 0; c < 8; ++c)  lo[c] = (_Float16)src[c * 256 + xx];
        #pragma unroll
        for (int c = 0; c < 8; ++c)  hi[c] = (_Float16)src[(c + 8) * 256 + xx];
        half8* dst = (half8*)(u_t + (size_t)bt * 4096 + xx * 16);
        dst[0] = lo; dst[1] = hi;
    }
}

// ---------------------------------------------------------------------------
// W2p[g][X][n] = sum_{b in g*64..} w[b] * clip(Aon[X,b,n]) ; grid 1024 x 128
// ---------------------------------------------------------------------------
__global__ void w2_kernel(const float* __restrict__ Aon, const float* __restrict__ wv,
                          float* __restrict__ W2p)
{
    int X = blockIdx.x >> 2, g = blockIdx.x & 3;
    int n = threadIdx.x;
    if (n >= 100) return;
    const float* base = Aon + (size_t)X * 25600 + (size_t)g * 6400 + n;
    float acc = 0.f;
    for (int b = 0; b < 64; ++b)
        acc += wv[g * 64 + b] * clip1(base[(size_t)b * 100]);
    W2p[((size_t)g * 256 + X) * 100 + n] = acc;
}

// ---------------------------------------------------------------------------
// R[bp][X][c] = sum_x xlast[bp][c][x] * V[X][x*16+c] ; grid 256 (X) x 256
// ---------------------------------------------------------------------------
__global__ __launch_bounds__(256) void R_kernel(const float* __restrict__ V,
                                                const float* __restrict__ xin,
                                                float* __restrict__ R)
{
    __shared__ float vrow[4096];
    int X = blockIdx.x, tid = threadIdx.x;
    {
        const float4* src = (const float4*)(V + (size_t)X * 4096);
        float4* dst = (float4*)vrow;
        for (int i = tid; i < 1024; i += 256) dst[i] = src[i];
    }
    __syncthreads();
    int bp = tid >> 6, c = (tid >> 2) & 15, g = tid & 3;
    const float* xl = xin + ((size_t)(bp * 12) + 11) * 4096 + c * 256;
    float p = 0.f;
    #pragma unroll 4
    for (int x = g * 64; x < g * 64 + 64; ++x)
        p += xl[x] * vrow[x * 16 + c];
    p += __shfl_xor(p, 1);
    p += __shfl_xor(p, 2);
    if (g == 0) R[((size_t)bp * 256 + X) * 16 + c] = p;
}

// ---------------------------------------------------------------------------
// GEMM: 128x128 tile, BK=64, double-buffered LDS via global_load_lds dwordx4,
// XOR-swizzled fragment reads (pre-swizzled global source), 2 barriers/step.
// grid = 768 = 48 bt * 4 tiles * KS(4) kc-chunks, XCD-major kc assignment.
// ---------------------------------------------------------------------------
__global__ __launch_bounds__(256) void gemm_kvt(
    const __half* __restrict__ Kh, const __half* __restrict__ Qh,
    const __half* __restrict__ u_t, float* __restrict__ kvtp, int q)
{
    __shared__ __half As[2][128][64];   // 32 KB
    __shared__ __half Bs[2][128][64];   // 32 KB
    __shared__ __half u_s[1024];        // 2 KB

    int bid = blockIdx.x;
    int work = (bid & 7) * q + (bid >> 3);     // XCD x gets contiguous works
    int kc = work / 192;
    int rem = work - kc * 192;
    int tile = rem / 48;
    int bt = rem - tile * 48;
    int Xb = (tile >> 1) * 128, Yb = (tile & 1) * 128;
    int kbase = kc * 1024;

    int tid = threadIdx.x;
    int wave = tid >> 6, lane = tid & 63;

    if (tid < 128)
        *(uint4*)&u_s[tid * 8] = *(const uint4*)(u_t + (size_t)bt * 4096 + kbase + tid * 8);

    // pre-swizzled per-lane global sources: lane l covers row +l/8, k-slot (l&7)^(l>>3)
    int lr = lane >> 3;
    int lk = lane & 7;
    int swz = ((lk ^ lr) << 3);                // halves
    const __half* gA = Kh + (size_t)(Xb + wave * 32 + lr) * 4096 + kbase + swz;
    const __half* gB = Qh + (size_t)(Yb + wave * 32 + lr) * 4096 + kbase + swz;

    int wr = (wave >> 1) * 64, wc = (wave & 1) * 64;
    int lrow = lane & 15, kg = lane >> 4;

    f32x4 acc[4][4];
    f32x4 zero = {0.f, 0.f, 0.f, 0.f};
    #pragma unroll
    for (int m = 0; m < 4; ++m)
        #pragma unroll
        for (int n = 0; n < 4; ++n) acc[m][n] = zero;

    // prologue stage into buf 0
    #pragma unroll
    for (int i = 0; i < 4; ++i) {
        gl_lds16(gA + (size_t)(i * 8) * 4096, &As[0][wave * 32 + i * 8][0]);
        gl_lds16(gB + (size_t)(i * 8) * 4096, &Bs[0][wave * 32 + i * 8][0]);
    }
    __syncthreads();

    int cur = 0;
    for (int s = 0; s < 16; ++s) {
        if (s < 15) {
            const __half* a = gA + (s + 1) * 64;
            const __half* b = gB + (s + 1) * 64;
            #pragma unroll
            for (int i = 0; i < 4; ++i) {
                gl_lds16(a + (size_t)(i * 8) * 4096, &As[cur ^ 1][wave * 32 + i * 8][0]);
                gl_lds16(b + (size_t)(i * 8) * 4096, &Bs[cur ^ 1][wave * 32 + i * 8][0]);
            }
        }
        #pragma unroll
        for (int kh = 0; kh < 2; ++kh) {
            uint4 uv = *(const uint4*)&u_s[s * 64 + kh * 32 + kg * 8];
            half8 af[4], bf[4];
            #pragma unroll
            for (int m = 0; m < 4; ++m) {
                int row = wr + m * 16 + lrow;
                int kbyte = (kh * 64 + kg * 16) ^ ((row & 7) << 4);
                af[m] = mul8(*(const uint4*)((const char*)&As[cur][row][0] + kbyte), uv);
            }
            #pragma unroll
            for (int n = 0; n < 4; ++n) {
                int row = wc + n * 16 + lrow;
                int kbyte = (kh * 64 + kg * 16) ^ ((row & 7) << 4);
                bf[n] = *(const half8*)((const char*)&Bs[cur][row][0] + kbyte);
            }
            #pragma unroll
            for (int m = 0; m < 4; ++m)
                #pragma unroll
                for (int n = 0; n < 4; ++n)
                    acc[m][n] = __builtin_amdgcn_mfma_f32_16x16x32_f16(af[m], bf[n], acc[m][n], 0, 0, 0);
        }
        __syncthreads();
        cur ^= 1;
    }

    // epilogue: D layout col = lane&15, row = (lane>>4)*4 + reg
    float* outp = kvtp + (size_t)kc * KVT_STRIDE + (size_t)bt * 65536;
    int row0 = Xb + wr + kg * 4;
    int col0 = Yb + wc + lrow;
    #pragma unroll
    for (int m = 0; m < 4; ++m)
        #pragma unroll
        for (int n = 0; n < 4; ++n)
            #pragma unroll
            for (int rr = 0; rr < 4; ++rr)
                outp[(size_t)(row0 + m * 16 + rr) * 256 + col0 + n * 16] = acc[m][n][rr];
}

// ---------------------------------------------------------------------------
// Sp[cb][bp][J][n] = sum_{k in 128-chunk cb} clip(Ano[k][n]) * kvt[bp*12+J][k]
// kvt materialized on the fly as sum of KS partials (L3-resident).
// ---------------------------------------------------------------------------
__global__ __launch_bounds__(256) void s_partial(const float* __restrict__ Ano,
                                                 const float* __restrict__ kvtp,
                                                 float* __restrict__ Sp)
{
    __shared__ float ano_f[12864];          // 128*100 + pad
    __shared__ float kvt_s[44][128];
    int cb = blockIdx.x;
    int k0 = cb * 128;
    int tid = threadIdx.x;

    {
        const float4* src = (const float4*)(Ano + (size_t)k0 * 100);
        float4* dst = (float4*)ano_f;
        for (int i = tid; i < 3200; i += 256) {
            float4 f = src[i];
            f.x = clip1(f.x); f.y = clip1(f.y); f.z = clip1(f.z); f.w = clip1(f.w);
            dst[i] = f;
        }
    }
    {
        for (int idx = tid; idx < 5632; idx += 256) {
            int rI = idx >> 7, k = idx & 127;
            int bpr = rI / 11, Jr = rI - bpr * 11;
            size_t off = (size_t)(bpr * 12 + Jr) * 65536 + k0 + k;
            float v = 0.f;
            #pragma unroll
            for (int c = 0; c < KS; ++c) v += kvtp[(size_t)c * KVT_STRIDE + off];
            kvt_s[rI][k] = v;
        }
    }
    __syncthreads();

    int lane = tid & 63;
    int bp = tid >> 6;
    bool has2 = lane < 36;
    float acc0[11], acc1[11];
    #pragma unroll
    for (int J = 0; J < 11; ++J) { acc0[J] = 0.f; acc1[J] = 0.f; }

    for (int k = 0; k < 128; k += 4) {
        f32x4 kv[11];
        #pragma unroll
        for (int J = 0; J < 11; ++J)
            kv[J] = *(const f32x4*)&kvt_s[bp * 11 + J][k];
        #pragma unroll
        for (int kk = 0; kk < 4; ++kk) {
            float a0 = ano_f[(k + kk) * 100 + lane];
            float a1r = ano_f[(k + kk) * 100 + 64 + lane];
            float a1 = has2 ? a1r : 0.f;
            #pragma unroll
            for (int J = 0; J < 11; ++J) {
                acc0[J] += kv[J][kk] * a0;
                acc1[J] += kv[J][kk] * a1;
            }
        }
    }
    float* outb = Sp + ((size_t)cb * 4 + bp) * 1100;
    #pragma unroll
    for (int J = 0; J < 11; ++J) {
        outb[J * 100 + lane] = acc0[J];
        if (has2) outb[J * 100 + 64 + lane] = acc1[J];
    }
}

// Sq[qq][bp*11+J][n] = sum_{cb in quarter qq} Sp[cb][bp][J][n] ; grid 176 x 128
__global__ void reduce_s(const float* __restrict__ Sp, float* __restrict__ Sq)
{
    int bid = blockIdx.x;
    int qq = bid & 3, idx = bid >> 2;       // idx 0..43
    int bp = idx / 11, J = idx - bp * 11;
    int t = threadIdx.x;
    if (t >= 100) return;
    float acc = 0.f;
    for (int c = qq * 128; c < qq * 128 + 128; ++c)
        acc += Sp[((size_t)c * 4 + bp) * 1100 + J * 100 + t];
    Sq[(size_t)(qq * 44 + idx) * 100 + t] = acc;
}

// c2[bp][n] = S[10] + sum_J A_seq[9-J]*S[J], S summed over 4 quarters ; 1 x 512
__global__ void c2_kernel(const float* __restrict__ Sq, const float* __restrict__ Ann,
                          float* __restrict__ c2)
{
    int t = threadIdx.x;
    int bp = t >> 7, n = t & 127;
    if (n >= 100) return;
    float S[11];
    #pragma unroll
    for (int J = 0; J < 11; ++J) {
        float s = 0.f;
        #pragma unroll
        for (int qq = 0; qq < 4; ++qq)
            s += Sq[(size_t)(qq * 44 + bp * 11 + J) * 100 + n];
        S[J] = s;
    }
    float a = Ann[n];
    float seq[10];
    float v = a;
    seq[0] = v;
    #pragma unroll
    for (int s = 1; s < 10; ++s) { v = clip1(v * a); seq[s] = v; }
    float r = S[10];
    #pragma unroll
    for (int J = 0; J < 10; ++J)
        r += seq[9 - J] * S[J];
    c2[bp * 100 + n] = r;
}

// hw[bp][X] = sum_x w[x]*Aoo[X,x]*kvt11[X,x] + sum_n c2[bp][n]*W2[X][n]
__global__ __launch_bounds__(256) void hw_kernel(const float* __restrict__ Aoo,
                                                 const float* __restrict__ wv,
                                                 const float* __restrict__ kvtp,
                                                 const float* __restrict__ W2p,
                                                 const float* __restrict__ c2,
                                                 float* __restrict__ hw)
{
    int bp = blockIdx.x >> 6, Xg = blockIdx.x & 63;
    int wave = threadIdx.x >> 6, lane = threadIdx.x & 63;
    int X = Xg * 4 + wave;
    size_t base = (size_t)(bp * 12 + 11) * 65536 + (size_t)X * 256;
    const float* ao = Aoo + (size_t)X * 256;
    float red = 0.f;
    #pragma unroll
    for (int qq = 0; qq < 4; ++qq) {
        int xx = qq * 64 + lane;
        float kvv = 0.f;
        #pragma unroll
        for (int c = 0; c < KS; ++c) kvv += kvtp[(size_t)c * KVT_STRIDE + base + xx];
        red += wv[xx] * ao[xx] * kvv;
    }
    float w2a = 0.f, w2b = 0.f;
    #pragma unroll
    for (int g = 0; g < 4; ++g) {
        w2a += W2p[((size_t)g * 256 + X) * 100 + lane];
        if (lane < 36) w2b += W2p[((size_t)g * 256 + X) * 100 + 64 + lane];
    }
    red += c2[bp * 100 + lane] * w2a;
    if (lane < 36)
        red += c2[bp * 100 + 64 + lane] * w2b;
    #pragma unroll
    for (int off = 32; off; off >>= 1) red += __shfl_xor(red, off);
    if (lane == 0) hw[bp * 256 + X] = red;
}

// y[bp*16+c] = sum_X hw[bp][X] * R[bp][X][c] ; grid 4 x 256
__global__ void y2_kernel(const float* __restrict__ hw, const float* __restrict__ R,
                          float* __restrict__ out)
{
    __shared__ float red[256];
    int bp = blockIdx.x, t = threadIdx.x;
    int Xg = t >> 4, c = t & 15;
    float p = 0.f;
    #pragma unroll
    for (int X = Xg * 16; X < Xg * 16 + 16; ++X)
        p += hw[bp * 256 + X] * R[((size_t)bp * 256 + X) * 16 + c];
    red[t] = p;
    __syncthreads();
    if (t < 16) {
        float s = 0.f;
        #pragma unroll
        for (int i = 0; i < 16; ++i) s += red[i * 16 + t];
        out[bp * 16 + t] = s;
    }
}

// ---------------------------------------------------------------------------
extern "C" void kernel_launch(void* const* d_in, const int* in_sizes, int n_in,
                              void* d_out, int out_size, void* d_ws, size_t ws_size,
                              hipStream_t stream)
{
    const float* x   = (const float*)d_in[0];
    const float* K   = (const float*)d_in[1];
    const float* Q   = (const float*)d_in[2];
    const float* V   = (const float*)d_in[3];
    const float* Aoo = (const float*)d_in[4];
    const float* Ann = (const float*)d_in[5];
    const float* Aon = (const float*)d_in[6];
    const float* Ano = (const float*)d_in[7];
    const float* wv  = (const float*)d_in[8];
    float* out = (float*)d_out;

    char* ws = (char*)d_ws;
    const size_t o_Qh   = 0;                                  // 2 MB
    const size_t o_Kh   = o_Qh + (size_t)2 * 1024 * 1024;     // 2 MB
    const size_t o_ut   = o_Kh + (size_t)2 * 1024 * 1024;     // 384 KB (pad .5 MB)
    const size_t o_kvtp = o_ut + (size_t)512 * 1024;          // KS*12 MB
    const size_t o_Sp   = o_kvtp + (size_t)KS * KVT_STRIDE * 4;
    const size_t o_Sq   = o_Sp + (size_t)512 * 4400 * 4;      // 176*100 f32
    const size_t o_c2   = o_Sq + (size_t)17600 * 4;
    const size_t o_W2   = o_c2 + 400 * 4 + 64;                // 4*256*100 f32
    const size_t o_hw   = o_W2 + (size_t)102400 * 4;
    const size_t o_R    = o_hw + 1024 * 4;                    // 4*256*16 f32

    __half* Qh  = (__half*)(ws + o_Qh);
    __half* Kh  = (__half*)(ws + o_Kh);
    __half* u_t = (__half*)(ws + o_ut);
    float* kvtp = (float*)(ws + o_kvtp);
    float* Sp   = (float*)(ws + o_Sp);
    float* Sq   = (float*)(ws + o_Sq);
    float* c2   = (float*)(ws + o_c2);
    float* W2p  = (float*)(ws + o_W2);
    float* hw   = (float*)(ws + o_hw);
    float* R    = (float*)(ws + o_R);

    hipLaunchKernelGGL(prep_kernel, dim3(2096), dim3(256), 0, stream, K, Q, x, Kh, Qh, u_t);
    hipLaunchKernelGGL(w2_kernel,   dim3(1024), dim3(128), 0, stream, Aon, wv, W2p);
    hipLaunchKernelGGL(R_kernel,    dim3(256),  dim3(256), 0, stream, V, x, R);
    hipLaunchKernelGGL(gemm_kvt,    dim3(768),  dim3(256), 0, stream, Kh, Qh, u_t, kvtp, 96);
    hipLaunchKernelGGL(s_partial,   dim3(512),  dim3(256), 0, stream, Ano, kvtp, Sp);
    hipLaunchKernelGGL(reduce_s,    dim3(176),  dim3(128), 0, stream, Sp, Sq);
    hipLaunchKernelGGL(c2_kernel,   dim3(1),    dim3(512), 0, stream, Sq, Ann, c2);
    hipLaunchKernelGGL(hw_kernel,   dim3(256),  dim3(256), 0, stream, Aoo, wv, kvtp, W2p, c2, hw);
    hipLaunchKernelGGL(y2_kernel,   dim3(4),    dim3(256), 0, stream, hw, R, out);
}